// Round 1
// baseline (787.403 us; speedup 1.0000x reference)
//
#include <hip/hip_runtime.h>

#define Bv 2
#define Nv 2048
#define Cv 512
#define Hv 8
#define Dv 64
#define SROW 2052   // 2048 + 4: stride%32==4 -> worst 2-way LDS conflict (free), 16B-aligned rows

typedef __attribute__((ext_vector_type(8))) short s16x8;
typedef __attribute__((ext_vector_type(4))) float f32x4;

__device__ __forceinline__ unsigned short f2bf(float f) {
  union { float f; unsigned u; } x; x.f = f;
  return (unsigned short)((x.u + 0x7fffu + ((x.u >> 16) & 1u)) >> 16);
}

__device__ __forceinline__ s16x8 cvt8(const float* p) {
  float4 a = *(const float4*)p;
  float4 b = *(const float4*)(p + 4);
  s16x8 r;
  r[0] = (short)f2bf(a.x); r[1] = (short)f2bf(a.y);
  r[2] = (short)f2bf(a.z); r[3] = (short)f2bf(a.w);
  r[4] = (short)f2bf(b.x); r[5] = (short)f2bf(b.y);
  r[6] = (short)f2bf(b.z); r[7] = (short)f2bf(b.w);
  return r;
}

// ---------------------------------------------------------------------------
// K1: y = x @ W^T + b for Wq/Wk/Wv (blockIdx.z picks matrix).
// Writes Q,K bf16 [B,H,N,D]; V transposed bf16 [B,H,D,N].
// WG = 64x64 output tile; wave w owns rows [w*16, w*16+16) x 64 cols.
// ---------------------------------------------------------------------------
__global__ __launch_bounds__(256) void proj_qkv(
    const float* __restrict__ x,
    const float* __restrict__ Wq, const float* __restrict__ bq,
    const float* __restrict__ Wk, const float* __restrict__ bk,
    const float* __restrict__ Wv, const float* __restrict__ bv,
    unsigned short* __restrict__ Qbf, unsigned short* __restrict__ Kbf,
    unsigned short* __restrict__ Vt) {
  const int lane = threadIdx.x & 63;
  const int wv   = threadIdx.x >> 6;
  const int l16  = lane & 15, quad = lane >> 4;
  const int mbase = blockIdx.x * 64 + wv * 16;
  const int nbase = blockIdx.y * 64;
  const int mat   = blockIdx.z;
  const float* W    = (mat == 0) ? Wq : (mat == 1) ? Wk : Wv;
  const float* bias = (mat == 0) ? bq : (mat == 1) ? bk : bv;

  f32x4 acc[4] = {};
  const int arow = mbase + l16;
  for (int kk = 0; kk < Cv; kk += 32) {
    s16x8 a = cvt8(x + (size_t)arow * Cv + kk + quad * 8);
#pragma unroll
    for (int ct = 0; ct < 4; ct++) {
      s16x8 bfr = cvt8(W + (size_t)(nbase + ct * 16 + l16) * Cv + kk + quad * 8);
      acc[ct] = __builtin_amdgcn_mfma_f32_16x16x32_bf16(a, bfr, acc[ct], 0, 0, 0);
    }
  }
#pragma unroll
  for (int ct = 0; ct < 4; ct++) {
    int n = nbase + ct * 16 + l16;         // output channel
    int h = n >> 6, d = n & 63;
    float bb = bias[n];
#pragma unroll
    for (int r = 0; r < 4; r++) {
      int m = mbase + quad * 4 + r;         // C/D layout: row = quad*4+reg, col = lane&15
      int bidx = m >> 11, nn = m & 2047;
      unsigned short v16 = f2bf(acc[ct][r] + bb);
      if (mat == 0)
        Qbf[(((size_t)bidx * Hv + h) * Nv + nn) * Dv + d] = v16;
      else if (mat == 1)
        Kbf[(((size_t)bidx * Hv + h) * Nv + nn) * Dv + d] = v16;
      else
        Vt[(((size_t)bidx * Hv + h) * Dv + d) * Nv + nn] = v16;
    }
  }
}

// ---------------------------------------------------------------------------
// K2: fused scores -> sparsemax -> PV for one (b,h) and 16 q-rows.
// S tile [16][2052] fp32 in LDS (~128 KB). attn written to d_out once.
// ---------------------------------------------------------------------------
__global__ __launch_bounds__(256) void attn_sparsemax(
    const unsigned short* __restrict__ Qbf, const unsigned short* __restrict__ Kbf,
    const unsigned short* __restrict__ Vtb, float* __restrict__ attn_out,
    float* __restrict__ O) {
  __shared__ float S[16 * SROW];
  __shared__ float tau_s[16];
  __shared__ float surv[16 * 64];

  const int lane = threadIdx.x & 63;
  const int wv   = threadIdx.x >> 6;
  const int l16  = lane & 15, quad = lane >> 4;
  const int bh    = blockIdx.x >> 7;          // / (N/16)
  const int qbase = (blockIdx.x & 127) << 4;
  const int b = bh >> 3, h = bh & 7;

  const unsigned short* Qh = Qbf + (size_t)bh * Nv * Dv;
  const unsigned short* Kh = Kbf + (size_t)bh * Nv * Dv;
  const unsigned short* Vh = Vtb + (size_t)bh * Dv * Nv;
  float* attn = attn_out + (size_t)bh * Nv * Nv + (size_t)qbase * Nv;

  // ---- phase 1: S = (Q K^T) * 1/sqrt(D) ----
  s16x8 a0 = *(const s16x8*)(Qh + (size_t)(qbase + l16) * Dv + quad * 8);
  s16x8 a1 = *(const s16x8*)(Qh + (size_t)(qbase + l16) * Dv + 32 + quad * 8);
  for (int t = 0; t < 32; t++) {
    int col0 = (t * 4 + wv) * 16;
    s16x8 b0 = *(const s16x8*)(Kh + (size_t)(col0 + l16) * Dv + quad * 8);
    s16x8 b1 = *(const s16x8*)(Kh + (size_t)(col0 + l16) * Dv + 32 + quad * 8);
    f32x4 c = {};
    c = __builtin_amdgcn_mfma_f32_16x16x32_bf16(a0, b0, c, 0, 0, 0);
    c = __builtin_amdgcn_mfma_f32_16x16x32_bf16(a1, b1, c, 0, 0, 0);
#pragma unroll
    for (int r = 0; r < 4; r++)
      S[(quad * 4 + r) * SROW + col0 + l16] = c[r] * 0.125f;
  }
  __syncthreads();

  // ---- phase 2: sparsemax per row (wave wv owns rows 4*wv..4*wv+3) ----
  const unsigned long long lt_mask = (1ull << lane) - 1ull;
  for (int i = 0; i < 4; i++) {
    int row = wv * 4 + i;
    float v[32];
#pragma unroll
    for (int t = 0; t < 32; t++) v[t] = S[row * SROW + lane + t * 64];
    float m = v[0];
#pragma unroll
    for (int t = 1; t < 32; t++) m = fmaxf(m, v[t]);
#pragma unroll
    for (int off = 32; off > 0; off >>= 1) m = fmaxf(m, __shfl_xor(m, off, 64));
    const float cut = m - 1.0f;  // tau >= max-1 always; entries <= cut never contribute

    // ballot-prefix compaction of candidates (> cut) into LDS, cap 64
    int base = 0;
#pragma unroll
    for (int t = 0; t < 32; t++) {
      bool keep = v[t] > cut;
      unsigned long long mk = __ballot(keep);
      if (keep) {
        int pos = base + __popcll(mk & lt_mask);
        if (pos < 64) surv[row * 64 + pos] = v[t];
      }
      base += __popcll(mk);
    }
    __syncthreads();  // uniform trip count across all waves
    int cnt = base;
    float lo = cut, hi = m;
    if (cnt <= 64) {
      float sv = (lane < cnt) ? surv[row * 64 + lane] : -1e30f;
      for (int it = 0; it < 22; it++) {
        float mid = 0.5f * (lo + hi);
        float s = fmaxf(sv - mid, 0.0f);
#pragma unroll
        for (int off = 32; off > 0; off >>= 1) s += __shfl_xor(s, off, 64);
        if (s > 1.0f) lo = mid; else hi = mid;
      }
    } else {  // structural fallback: bisect over the full row
      for (int it = 0; it < 22; it++) {
        float mid = 0.5f * (lo + hi);
        float s = 0.0f;
#pragma unroll
        for (int t = 0; t < 32; t++) s += fmaxf(v[t] - mid, 0.0f);
#pragma unroll
        for (int off = 32; off > 0; off >>= 1) s += __shfl_xor(s, off, 64);
        if (s > 1.0f) lo = mid; else hi = mid;
      }
    }
    float tau = 0.5f * (lo + hi);
    if (lane == 0) tau_s[row] = tau;
    // write attn row (coalesced, 256B per step per wave)
#pragma unroll
    for (int t = 0; t < 32; t++)
      attn[(size_t)row * Nv + lane + t * 64] = fmaxf(v[t] - tau, 0.0f);
    __syncthreads();
  }
  __syncthreads();

  // ---- phase 3: O(16 x 64) = P V; wave wv owns dims [wv*16, wv*16+16) ----
  f32x4 acc = {};
  const float taur = tau_s[l16];  // A-layout: m = lane&15
  for (int kc = 0; kc < Nv; kc += 32) {
    const float* sp = &S[l16 * SROW + kc + quad * 8];
    float4 s0 = *(const float4*)sp;
    float4 s1 = *(const float4*)(sp + 4);
    s16x8 af;
    af[0] = (short)f2bf(fmaxf(s0.x - taur, 0.0f));
    af[1] = (short)f2bf(fmaxf(s0.y - taur, 0.0f));
    af[2] = (short)f2bf(fmaxf(s0.z - taur, 0.0f));
    af[3] = (short)f2bf(fmaxf(s0.w - taur, 0.0f));
    af[4] = (short)f2bf(fmaxf(s1.x - taur, 0.0f));
    af[5] = (short)f2bf(fmaxf(s1.y - taur, 0.0f));
    af[6] = (short)f2bf(fmaxf(s1.z - taur, 0.0f));
    af[7] = (short)f2bf(fmaxf(s1.w - taur, 0.0f));
    s16x8 bfr = *(const s16x8*)(Vh + (size_t)(wv * 16 + l16) * Nv + kc + quad * 8);
    acc = __builtin_amdgcn_mfma_f32_16x16x32_bf16(af, bfr, acc, 0, 0, 0);
  }
#pragma unroll
  for (int r = 0; r < 4; r++) {
    int n = qbase + quad * 4 + r;
    int c = h * Dv + wv * 16 + l16;
    O[((size_t)b * Nv + n) * Cv + c] = acc[r];
  }
}

// ---------------------------------------------------------------------------
// K3: out = O @ Wo^T + bo  (fp32 out to d_out)
// ---------------------------------------------------------------------------
__global__ __launch_bounds__(256) void proj_out(
    const float* __restrict__ O, const float* __restrict__ Wo,
    const float* __restrict__ bo, float* __restrict__ out) {
  const int lane = threadIdx.x & 63;
  const int wv   = threadIdx.x >> 6;
  const int l16  = lane & 15, quad = lane >> 4;
  const int mbase = blockIdx.x * 64 + wv * 16;
  const int nbase = blockIdx.y * 64;

  f32x4 acc[4] = {};
  for (int kk = 0; kk < Cv; kk += 32) {
    s16x8 a = cvt8(O + (size_t)(mbase + l16) * Cv + kk + quad * 8);
#pragma unroll
    for (int ct = 0; ct < 4; ct++) {
      s16x8 bfr = cvt8(Wo + (size_t)(nbase + ct * 16 + l16) * Cv + kk + quad * 8);
      acc[ct] = __builtin_amdgcn_mfma_f32_16x16x32_bf16(a, bfr, acc[ct], 0, 0, 0);
    }
  }
#pragma unroll
  for (int ct = 0; ct < 4; ct++) {
    int n = nbase + ct * 16 + l16;
    float bb = bo[n];
#pragma unroll
    for (int r = 0; r < 4; r++) {
      int m = mbase + quad * 4 + r;
      out[(size_t)m * Cv + n] = acc[ct][r] + bb;
    }
  }
}

extern "C" void kernel_launch(void* const* d_in, const int* in_sizes, int n_in,
                              void* d_out, int out_size, void* d_ws, size_t ws_size,
                              hipStream_t stream) {
  (void)in_sizes; (void)n_in; (void)out_size; (void)ws_size;
  const float* x  = (const float*)d_in[0];
  const float* Wq = (const float*)d_in[1];
  const float* bq = (const float*)d_in[2];
  const float* Wk = (const float*)d_in[3];
  const float* bk = (const float*)d_in[4];
  const float* Wv = (const float*)d_in[5];
  const float* bv = (const float*)d_in[6];
  const float* Wo = (const float*)d_in[7];
  const float* bo = (const float*)d_in[8];

  float* out  = (float*)d_out;                       // [B,N,C]
  float* attn = out + (size_t)Bv * Nv * Cv;          // [B,H,N,N]

  const size_t qkv_elems = (size_t)Bv * Hv * Nv * Dv;   // 2,097,152
  unsigned short* Qbf = (unsigned short*)d_ws;
  unsigned short* Kbf = Qbf + qkv_elems;
  unsigned short* Vt  = Kbf + qkv_elems;
  float* O = (float*)(Vt + qkv_elems);                  // [B,N,C] fp32

  proj_qkv<<<dim3((Bv * Nv) / 64, Cv / 64, 3), 256, 0, stream>>>(
      x, Wq, bq, Wk, bk, Wv, bv, Qbf, Kbf, Vt);
  attn_sparsemax<<<dim3(Bv * Hv * (Nv / 16)), 256, 0, stream>>>(
      Qbf, Kbf, Vt, attn, O);
  proj_out<<<dim3((Bv * Nv) / 64, Cv / 64), 256, 0, stream>>>(O, Wo, bo, out);
}

// Round 2
// 557.692 us; speedup vs baseline: 1.4119x; 1.4119x over previous
//
#include <hip/hip_runtime.h>

#define Bv 2
#define Nv 2048
#define Cv 512
#define Hv 8
#define Dv 64
#define CAP 256   // candidate cap per row; P(overflow) ~ e^-32 for N(0,1) scores

typedef __attribute__((ext_vector_type(8))) short s16x8;
typedef __attribute__((ext_vector_type(4))) float f32x4;

__device__ __forceinline__ unsigned short f2bf(float f) {
  union { float f; unsigned u; } x; x.f = f;
  return (unsigned short)((x.u + 0x7fffu + ((x.u >> 16) & 1u)) >> 16);
}
__device__ __forceinline__ float bf2f(unsigned short u) {
  union { unsigned u; float f; } x; x.u = ((unsigned)u) << 16;
  return x.f;
}

// ---------------------------------------------------------------------------
// K0: convert x, Wq, Wk, Wv, Wo to bf16 (blockIdx.y selects tensor)
// ---------------------------------------------------------------------------
__global__ __launch_bounds__(256) void cvt5(
    const float* __restrict__ x, const float* __restrict__ wq,
    const float* __restrict__ wk, const float* __restrict__ wv_,
    const float* __restrict__ wo,
    unsigned short* __restrict__ xb, unsigned short* __restrict__ wqb,
    unsigned short* __restrict__ wkb, unsigned short* __restrict__ wvb,
    unsigned short* __restrict__ wob) {
  const float* s; unsigned short* d; int n;
  switch (blockIdx.y) {
    case 0: s = x;   d = xb;  n = Bv * Nv * Cv; break;
    case 1: s = wq;  d = wqb; n = Cv * Cv; break;
    case 2: s = wk;  d = wkb; n = Cv * Cv; break;
    case 3: s = wv_; d = wvb; n = Cv * Cv; break;
    default: s = wo; d = wob; n = Cv * Cv; break;
  }
  int i = (blockIdx.x * 256 + threadIdx.x) * 4;
  if (i < n) {
    float4 v = *(const float4*)(s + i);
    ushort4 o;
    o.x = f2bf(v.x); o.y = f2bf(v.y); o.z = f2bf(v.z); o.w = f2bf(v.w);
    *(ushort4*)(d + i) = o;
  }
}

// ---------------------------------------------------------------------------
// K1: Q/K/V = x @ W^T + b, all bf16 in, bf16 out [B,H,N,D]
// ---------------------------------------------------------------------------
__global__ __launch_bounds__(256) void proj_qkv(
    const unsigned short* __restrict__ xb,
    const unsigned short* __restrict__ wqb, const float* __restrict__ bq,
    const unsigned short* __restrict__ wkb, const float* __restrict__ bk,
    const unsigned short* __restrict__ wvb, const float* __restrict__ bv,
    unsigned short* __restrict__ Qbf, unsigned short* __restrict__ Kbf,
    unsigned short* __restrict__ Vbf) {
  const int lane = threadIdx.x & 63;
  const int wv   = threadIdx.x >> 6;
  const int l16  = lane & 15, quad = lane >> 4;
  const int mbase = blockIdx.x * 64 + wv * 16;
  const int nbase = blockIdx.y * 64;
  const int mat   = blockIdx.z;
  const unsigned short* W = (mat == 0) ? wqb : (mat == 1) ? wkb : wvb;
  const float* bias = (mat == 0) ? bq : (mat == 1) ? bk : bv;
  unsigned short* dst = (mat == 0) ? Qbf : (mat == 1) ? Kbf : Vbf;

  f32x4 acc[4] = {};
  for (int kk = 0; kk < Cv; kk += 32) {
    s16x8 a = *(const s16x8*)(xb + (size_t)(mbase + l16) * Cv + kk + quad * 8);
#pragma unroll
    for (int ct = 0; ct < 4; ct++) {
      s16x8 bfr = *(const s16x8*)(W + (size_t)(nbase + ct * 16 + l16) * Cv + kk + quad * 8);
      acc[ct] = __builtin_amdgcn_mfma_f32_16x16x32_bf16(a, bfr, acc[ct], 0, 0, 0);
    }
  }
#pragma unroll
  for (int ct = 0; ct < 4; ct++) {
    int n = nbase + ct * 16 + l16;
    int h = n >> 6, d = n & 63;
    float bb = bias[n];
#pragma unroll
    for (int r = 0; r < 4; r++) {
      int m = mbase + quad * 4 + r;  // C/D: row=quad*4+reg, col=lane&15
      int bidx = m >> 11, nn = m & 2047;
      dst[(((size_t)bidx * Hv + h) * Nv + nn) * Dv + d] = f2bf(acc[ct][r] + bb);
    }
  }
}

// ---------------------------------------------------------------------------
// K2: sparse fused attention. Per (b,h,16 q-rows):
//  pass A: QK^T row maxes; pass B: compact candidates > max-1 (LDS, cap 256);
//  bisection for tau on candidates; scatter attn nonzeros (attn pre-zeroed
//  by memset); sparse PV in fp32 VALU; O written bf16.
// ---------------------------------------------------------------------------
__global__ __launch_bounds__(256) void attn_sparse(
    const unsigned short* __restrict__ Qbf, const unsigned short* __restrict__ Kbf,
    const unsigned short* __restrict__ Vbf, float* __restrict__ attn_out,
    unsigned short* __restrict__ Obf) {
  __shared__ float rowmax_w[4][16];
  __shared__ float mrow[16];
  __shared__ float candv[16][CAP];
  __shared__ int   candi[16][CAP];
  __shared__ int   cnt[16];
  __shared__ float lo_s[16], hi_s[16], sum_s[16], taud[16];
  __shared__ int   oflow;

  const int lane = threadIdx.x & 63;
  const int wv   = threadIdx.x >> 6;
  const int l16  = lane & 15, quad = lane >> 4;
  const int bh    = blockIdx.x >> 7;
  const int qbase = (blockIdx.x & 127) << 4;
  const int b = bh >> 3, h = bh & 7;

  const unsigned short* Qh = Qbf + (size_t)bh * Nv * Dv;
  const unsigned short* Kh = Kbf + (size_t)bh * Nv * Dv;
  const unsigned short* Vh = Vbf + (size_t)bh * Nv * Dv;
  float* attn_bh = attn_out + (size_t)bh * Nv * Nv;

  if (threadIdx.x < 16) cnt[threadIdx.x] = 0;
  if (threadIdx.x == 0) oflow = 0;

  s16x8 a0 = *(const s16x8*)(Qh + (size_t)(qbase + l16) * Dv + quad * 8);
  s16x8 a1 = *(const s16x8*)(Qh + (size_t)(qbase + l16) * Dv + 32 + quad * 8);

  // ---- pass A: row maxes (raw dot; scale at end) ----
  float rm[4] = {-1e30f, -1e30f, -1e30f, -1e30f};
  for (int t = 0; t < 32; t++) {
    int col0 = (t * 4 + wv) * 16;
    s16x8 b0 = *(const s16x8*)(Kh + (size_t)(col0 + l16) * Dv + quad * 8);
    s16x8 b1 = *(const s16x8*)(Kh + (size_t)(col0 + l16) * Dv + 32 + quad * 8);
    f32x4 c = {};
    c = __builtin_amdgcn_mfma_f32_16x16x32_bf16(a0, b0, c, 0, 0, 0);
    c = __builtin_amdgcn_mfma_f32_16x16x32_bf16(a1, b1, c, 0, 0, 0);
#pragma unroll
    for (int r = 0; r < 4; r++) rm[r] = fmaxf(rm[r], c[r]);
  }
#pragma unroll
  for (int off = 1; off <= 8; off <<= 1)
#pragma unroll
    for (int r = 0; r < 4; r++) rm[r] = fmaxf(rm[r], __shfl_xor(rm[r], off, 64));
  if (l16 == 0) {
#pragma unroll
    for (int r = 0; r < 4; r++) rowmax_w[wv][quad * 4 + r] = rm[r];
  }
  __syncthreads();
  float m[4];
#pragma unroll
  for (int r = 0; r < 4; r++) {
    int row = quad * 4 + r;
    float mm = fmaxf(fmaxf(rowmax_w[0][row], rowmax_w[1][row]),
                     fmaxf(rowmax_w[2][row], rowmax_w[3][row]));
    m[r] = mm * 0.125f;
  }
  if (wv == 0 && l16 == 0) {
#pragma unroll
    for (int r = 0; r < 4; r++) mrow[quad * 4 + r] = m[r];
  }

  // ---- pass B: compact candidates > max-1 ----
  for (int t = 0; t < 32; t++) {
    int col0 = (t * 4 + wv) * 16;
    s16x8 b0 = *(const s16x8*)(Kh + (size_t)(col0 + l16) * Dv + quad * 8);
    s16x8 b1 = *(const s16x8*)(Kh + (size_t)(col0 + l16) * Dv + 32 + quad * 8);
    f32x4 c = {};
    c = __builtin_amdgcn_mfma_f32_16x16x32_bf16(a0, b0, c, 0, 0, 0);
    c = __builtin_amdgcn_mfma_f32_16x16x32_bf16(a1, b1, c, 0, 0, 0);
#pragma unroll
    for (int r = 0; r < 4; r++) {
      float val = c[r] * 0.125f;
      if (val > m[r] - 1.0f) {
        int row = quad * 4 + r;
        int pos = atomicAdd(&cnt[row], 1);
        if (pos < CAP) { candv[row][pos] = val; candi[row][pos] = col0 + l16; }
      }
    }
  }
  __syncthreads();
  if (threadIdx.x < 16 && cnt[threadIdx.x] > CAP) oflow = 1;
  __syncthreads();

  float tau[4];
  if (oflow == 0) {
    // ---- bisection on candidate lists; wave wv owns rows wv*4..wv*4+3 ----
    float cv[4][4], lo[4], hi[4];
#pragma unroll
    for (int i = 0; i < 4; i++) {
      int row = wv * 4 + i;
      int c_ = cnt[row];
#pragma unroll
      for (int j = 0; j < 4; j++) {
        int p = lane + j * 64;
        cv[i][j] = (p < c_) ? candv[row][p] : -1e30f;
      }
      lo[i] = mrow[row] - 1.0f; hi[i] = mrow[row];
    }
    for (int it = 0; it < 22; it++) {
      float mid[4], s[4];
#pragma unroll
      for (int i = 0; i < 4; i++) {
        mid[i] = 0.5f * (lo[i] + hi[i]);
        float ss = 0.0f;
#pragma unroll
        for (int j = 0; j < 4; j++) ss += fmaxf(cv[i][j] - mid[i], 0.0f);
        s[i] = ss;
      }
#pragma unroll
      for (int off = 32; off > 0; off >>= 1)
#pragma unroll
        for (int i = 0; i < 4; i++) s[i] += __shfl_xor(s[i], off, 64);
#pragma unroll
      for (int i = 0; i < 4; i++) {
        if (s[i] > 1.0f) lo[i] = mid[i]; else hi[i] = mid[i];
      }
    }
#pragma unroll
    for (int i = 0; i < 4; i++) tau[i] = 0.5f * (lo[i] + hi[i]);

    // ---- scatter attn nonzeros ----
#pragma unroll
    for (int i = 0; i < 4; i++) {
      int row = wv * 4 + i;
      float* arow = attn_bh + (size_t)(qbase + row) * Nv;
      int c_ = cnt[row];
#pragma unroll
      for (int j = 0; j < 4; j++) {
        int p = lane + j * 64;
        if (p < c_) {
          float v = cv[i][j] - tau[i];
          if (v > 0.0f) arow[candi[row][p]] = v;
        }
      }
    }
  } else {
    // ---- pathological fallback: dense bisection via recompute (never taken
    //      for Gaussian-scale inputs; structural correctness only) ----
    if (threadIdx.x < 16) { lo_s[threadIdx.x] = mrow[threadIdx.x] - 1.0f; hi_s[threadIdx.x] = mrow[threadIdx.x]; }
    __syncthreads();
    for (int it = 0; it < 26; it++) {
      if (threadIdx.x < 16) sum_s[threadIdx.x] = 0.0f;
      __syncthreads();
      float part[4] = {0, 0, 0, 0};
      for (int t = 0; t < 32; t++) {
        int col0 = (t * 4 + wv) * 16;
        s16x8 b0 = *(const s16x8*)(Kh + (size_t)(col0 + l16) * Dv + quad * 8);
        s16x8 b1 = *(const s16x8*)(Kh + (size_t)(col0 + l16) * Dv + 32 + quad * 8);
        f32x4 c = {};
        c = __builtin_amdgcn_mfma_f32_16x16x32_bf16(a0, b0, c, 0, 0, 0);
        c = __builtin_amdgcn_mfma_f32_16x16x32_bf16(a1, b1, c, 0, 0, 0);
#pragma unroll
        for (int r = 0; r < 4; r++) {
          int row = quad * 4 + r;
          float mid = 0.5f * (lo_s[row] + hi_s[row]);
          part[r] += fmaxf(c[r] * 0.125f - mid, 0.0f);
        }
      }
#pragma unroll
      for (int off = 1; off <= 8; off <<= 1)
#pragma unroll
        for (int r = 0; r < 4; r++) part[r] += __shfl_xor(part[r], off, 64);
      if (l16 == 0) {
#pragma unroll
        for (int r = 0; r < 4; r++) atomicAdd(&sum_s[quad * 4 + r], part[r]);
      }
      __syncthreads();
      if (threadIdx.x < 16) {
        float mid = 0.5f * (lo_s[threadIdx.x] + hi_s[threadIdx.x]);
        if (sum_s[threadIdx.x] > 1.0f) lo_s[threadIdx.x] = mid; else hi_s[threadIdx.x] = mid;
      }
      __syncthreads();
    }
    if (threadIdx.x < 16) taud[threadIdx.x] = 0.5f * (lo_s[threadIdx.x] + hi_s[threadIdx.x]);
    __syncthreads();
    // dense attn write
    for (int t = 0; t < 32; t++) {
      int col0 = (t * 4 + wv) * 16;
      s16x8 b0 = *(const s16x8*)(Kh + (size_t)(col0 + l16) * Dv + quad * 8);
      s16x8 b1 = *(const s16x8*)(Kh + (size_t)(col0 + l16) * Dv + 32 + quad * 8);
      f32x4 c = {};
      c = __builtin_amdgcn_mfma_f32_16x16x32_bf16(a0, b0, c, 0, 0, 0);
      c = __builtin_amdgcn_mfma_f32_16x16x32_bf16(a1, b1, c, 0, 0, 0);
#pragma unroll
      for (int r = 0; r < 4; r++) {
        int row = quad * 4 + r;
        attn_bh[(size_t)(qbase + row) * Nv + col0 + l16] =
            fmaxf(c[r] * 0.125f - taud[row], 0.0f);
      }
    }
    __threadfence();
    __syncthreads();
#pragma unroll
    for (int i = 0; i < 4; i++) tau[i] = taud[wv * 4 + i];
  }

  // ---- sparse PV (fp32 VALU); lane = output dim ----
  float o[4] = {0, 0, 0, 0};
  if (oflow == 0) {
#pragma unroll
    for (int i = 0; i < 4; i++) {
      int row = wv * 4 + i;
      int c_ = cnt[row] < CAP ? cnt[row] : CAP;
      for (int jj = 0; jj < c_; jj++) {
        float p = candv[row][jj] - tau[i];
        if (p > 0.0f) {
          int k = candi[row][jj];
          o[i] += p * bf2f(Vh[(size_t)k * Dv + lane]);
        }
      }
    }
  } else {
    // slow, correct: read back dense attn row (never taken in practice)
#pragma unroll
    for (int i = 0; i < 4; i++) {
      int row = wv * 4 + i;
      const float* arow = attn_bh + (size_t)(qbase + row) * Nv;
      for (int k = 0; k < Nv; k++) {
        float p = arow[k];
        if (p > 0.0f) o[i] += p * bf2f(Vh[(size_t)k * Dv + lane]);
      }
    }
  }
#pragma unroll
  for (int i = 0; i < 4; i++) {
    int row = wv * 4 + i;
    Obf[((size_t)(b * Nv + qbase + row)) * Cv + h * Dv + lane] = f2bf(o[i]);
  }
}

// ---------------------------------------------------------------------------
// K3: out = O @ Wo^T + bo (bf16 in, fp32 out)
// ---------------------------------------------------------------------------
__global__ __launch_bounds__(256) void proj_out(
    const unsigned short* __restrict__ Obf, const unsigned short* __restrict__ wob,
    const float* __restrict__ bo, float* __restrict__ out) {
  const int lane = threadIdx.x & 63;
  const int wv   = threadIdx.x >> 6;
  const int l16  = lane & 15, quad = lane >> 4;
  const int mbase = blockIdx.x * 64 + wv * 16;
  const int nbase = blockIdx.y * 64;

  f32x4 acc[4] = {};
  for (int kk = 0; kk < Cv; kk += 32) {
    s16x8 a = *(const s16x8*)(Obf + (size_t)(mbase + l16) * Cv + kk + quad * 8);
#pragma unroll
    for (int ct = 0; ct < 4; ct++) {
      s16x8 bfr = *(const s16x8*)(wob + (size_t)(nbase + ct * 16 + l16) * Cv + kk + quad * 8);
      acc[ct] = __builtin_amdgcn_mfma_f32_16x16x32_bf16(a, bfr, acc[ct], 0, 0, 0);
    }
  }
#pragma unroll
  for (int ct = 0; ct < 4; ct++) {
    int n = nbase + ct * 16 + l16;
    float bb = bo[n];
#pragma unroll
    for (int r = 0; r < 4; r++) {
      int m = mbase + quad * 4 + r;
      out[(size_t)m * Cv + n] = acc[ct][r] + bb;
    }
  }
}

extern "C" void kernel_launch(void* const* d_in, const int* in_sizes, int n_in,
                              void* d_out, int out_size, void* d_ws, size_t ws_size,
                              hipStream_t stream) {
  (void)in_sizes; (void)n_in; (void)out_size; (void)ws_size;
  const float* x  = (const float*)d_in[0];
  const float* Wq = (const float*)d_in[1];
  const float* bq = (const float*)d_in[2];
  const float* Wk = (const float*)d_in[3];
  const float* bk = (const float*)d_in[4];
  const float* Wv = (const float*)d_in[5];
  const float* bv = (const float*)d_in[6];
  const float* Wo = (const float*)d_in[7];
  const float* bo = (const float*)d_in[8];

  float* out  = (float*)d_out;                       // [B,N,C]
  float* attn = out + (size_t)Bv * Nv * Cv;          // [B,H,N,N]

  unsigned short* xb  = (unsigned short*)d_ws;
  unsigned short* wqb = xb  + (size_t)Bv * Nv * Cv;  // +2097152
  unsigned short* wkb = wqb + (size_t)Cv * Cv;
  unsigned short* wvb = wkb + (size_t)Cv * Cv;
  unsigned short* wob = wvb + (size_t)Cv * Cv;
  unsigned short* Qbf = wob + (size_t)Cv * Cv;
  unsigned short* Kbf = Qbf + (size_t)Bv * Hv * Nv * Dv;
  unsigned short* Vbf = Kbf + (size_t)Bv * Hv * Nv * Dv;
  unsigned short* Obf = Vbf + (size_t)Bv * Hv * Nv * Dv;

  hipMemsetAsync(attn, 0, (size_t)Bv * Hv * Nv * Nv * sizeof(float), stream);

  cvt5<<<dim3((Bv * Nv * Cv) / 4 / 256, 5), 256, 0, stream>>>(
      x, Wq, Wk, Wv, Wo, xb, wqb, wkb, wvb, wob);
  proj_qkv<<<dim3((Bv * Nv) / 64, Cv / 64, 3), 256, 0, stream>>>(
      xb, wqb, bq, wkb, bk, wvb, bv, Qbf, Kbf, Vbf);
  attn_sparse<<<dim3(Bv * Hv * (Nv / 16)), 256, 0, stream>>>(
      Qbf, Kbf, Vbf, attn, Obf);
  proj_out<<<dim3((Bv * Nv) / 64, Cv / 64), 256, 0, stream>>>(Obf, wob, bo, out);
}